// Round 1
// baseline (1556.563 us; speedup 1.0000x reference)
//
#include <hip/hip_runtime.h>

// CrossNet B=16384, D=1024, 4 layers — single persistent kernel.
//
// Key idea: the residual (64 MB) lives in REGISTERS for the whole net.
//   grid = 512 blocks x 256 threads = 2 blocks/CU x 256 CUs (co-resident).
//   Each thread owns 32 rows x 4 cols = 32 float4 = 128 VGPRs of residual.
//   __launch_bounds__(256, 2) caps VGPR at 256 -> 2 blocks/CU is
//   occupancy-guaranteed (LDS use is 128 B), so the manual grid barrier
//   cannot deadlock: all 512 blocks are always simultaneously resident.
//
// Per layer:
//   1. row dots: block covers a full row (256 thr x 4 cols); wave butterfly
//      + 128 B LDS cross-wave reduce, double-buffered (1 barrier / 4 rows).
//   2. update res += x0*s + b in registers; accumulate per-column sum/sumsq.
//   3. write per-block column partials (4 MB) -> grid barrier ->
//      256 stat blocks (wave 0, 4 cols each) reduce 512 partials/column ->
//      scale/shift -> grid barrier -> normalize registers in place.
// Layer 0: x0 == res registers, no global x0 read.
// After layer 3: normalized registers stored to out. No finalize pass.
//
// Memory traffic: x read once from HBM (64 MB), x0 re-read layers 1-3 from
// L3 (fits: 64 MB < 256 MB IC), 4x8 MB partials, 64 MB output write.
// vs previous version's ~900 MB and 13 serialized dispatches.

#define BB 16384
#define DD 1024
#define NL 4
#define BN_EPS 1e-5f

#define GRID_   512   // MUST equal 2 blocks/CU * 256 CUs (co-residency)
#define NTHR    256
#define ROWS    32    // BB / GRID_
#define CHUNK   4
#define NCHUNK  8     // ROWS / CHUNK
#define STATB   256   // stat blocks, 4 columns each (wave 0 only)
#define NSYNC   8     // 2 barriers per layer

// All-resident grid barrier. Release: every thread fences (drains its own
// stores + L2 writeback for cross-XCD visibility) before block arrival.
// Acquire: fence after the spin so subsequent reads see other XCDs' data.
__device__ __forceinline__ void grid_barrier(unsigned int* sync_, int slot) {
    __threadfence();
    __syncthreads();
    if (threadIdx.x == 0) {
        atomicAdd(sync_ + slot, 1u);   // device scope by default on gfx950
        while (__hip_atomic_load(sync_ + slot, __ATOMIC_ACQUIRE,
                                 __HIP_MEMORY_SCOPE_AGENT) < (unsigned)GRID_) {
            __builtin_amdgcn_s_sleep(2);
        }
    }
    __syncthreads();
    __threadfence();
}

__global__ void init_sync(unsigned int* sync_) {
    if (threadIdx.x < NSYNC) sync_[threadIdx.x] = 0u;
}

__global__ __launch_bounds__(NTHR, 2) void crossnet_persistent(
    const float* __restrict__ x,     // (B,D) input == x0
    const float* __restrict__ ww,    // (NL,D)
    const float* __restrict__ wb,    // (NL,D)
    float* __restrict__ out,         // (B,D)
    float* __restrict__ Psum,        // (GRID_,D) per-block column sums
    float* __restrict__ Psq,         // (GRID_,D) per-block column sumsq
    float* __restrict__ scale,       // (D)
    float* __restrict__ shift,       // (D)
    unsigned int* __restrict__ sync_)
{
    __shared__ __align__(16) float red[2][CHUNK][4];  // [buf][row][wave]

    const int tid  = threadIdx.x;
    const int lane = tid & 63;
    const int wv   = tid >> 6;
    const int c    = tid << 2;           // this thread's 4 columns
    const int blk  = blockIdx.x;
    const int r0   = blk * ROWS;

    // Residual state: 32 rows x 4 cols, lives in VGPRs for all 4 layers.
    float4 res[ROWS];
    #pragma unroll
    for (int i = 0; i < ROWS; ++i)
        res[i] = *(const float4*)(x + (size_t)(r0 + i) * DD + c);

    #pragma unroll 1
    for (int l = 0; l < NL; ++l) {
        const float4 w4 = *(const float4*)(ww + l * DD + c);
        const float4 b4 = *(const float4*)(wb + l * DD + c);

        float4 asum = make_float4(0.f, 0.f, 0.f, 0.f);
        float4 asq  = make_float4(0.f, 0.f, 0.f, 0.f);

        #pragma unroll
        for (int ch = 0; ch < NCHUNK; ++ch) {
            // Issue x0 loads early (hidden under shuffles + barrier).
            float4 xv[CHUNK];
            if (l > 0) {
                #pragma unroll
                for (int i = 0; i < CHUNK; ++i)
                    xv[i] = *(const float4*)(
                        x + (size_t)(r0 + ch * CHUNK + i) * DD + c);
            }

            // Row-dot partials from registers.
            float p[CHUNK];
            #pragma unroll
            for (int i = 0; i < CHUNK; ++i) {
                const float4 v = res[ch * CHUNK + i];
                p[i] = v.x * w4.x + v.y * w4.y + v.z * w4.z + v.w * w4.w;
            }
            // Wave-64 butterfly.
            #pragma unroll
            for (int off = 32; off; off >>= 1) {
                #pragma unroll
                for (int i = 0; i < CHUNK; ++i)
                    p[i] += __shfl_down(p[i], off, 64);
            }
            // Cross-wave via 128 B LDS, double-buffered -> 1 barrier/chunk.
            const int slot = ch & 1;
            if (lane == 0) {
                #pragma unroll
                for (int i = 0; i < CHUNK; ++i)
                    red[slot][i][wv] = p[i];
            }
            __syncthreads();

            #pragma unroll
            for (int i = 0; i < CHUNK; ++i) {
                const float4 rr = *(const float4*)red[slot][i];  // broadcast
                const float s = (rr.x + rr.y) + (rr.z + rr.w);
                float4 v = res[ch * CHUNK + i];
                const float4 xi = (l == 0) ? v : xv[i];  // layer 0: x0 == res
                float4 n;
                n.x = fmaf(xi.x, s, v.x) + b4.x;
                n.y = fmaf(xi.y, s, v.y) + b4.y;
                n.z = fmaf(xi.z, s, v.z) + b4.z;
                n.w = fmaf(xi.w, s, v.w) + b4.w;
                res[ch * CHUNK + i] = n;
                asum.x += n.x; asum.y += n.y; asum.z += n.z; asum.w += n.w;
                asq.x = fmaf(n.x, n.x, asq.x);
                asq.y = fmaf(n.y, n.y, asq.y);
                asq.z = fmaf(n.z, n.z, asq.z);
                asq.w = fmaf(n.w, n.w, asq.w);
            }
        }

        // Per-block column partials (thread exclusively owns its 4 cols).
        *(float4*)(Psum + (size_t)blk * DD + c) = asum;
        *(float4*)(Psq  + (size_t)blk * DD + c) = asq;

        grid_barrier(sync_, 2 * l);

        // Column stats: 256 blocks, wave 0 each, 4 columns per block.
        // lane k sums partial-rows {k, k+64, ..., k+448}; 6-level butterfly.
        if (blk < STATB && wv == 0) {
            const int cj = blk * 4;
            float4 s4 = make_float4(0.f, 0.f, 0.f, 0.f);
            float4 q4 = make_float4(0.f, 0.f, 0.f, 0.f);
            #pragma unroll
            for (int i = 0; i < GRID_ / 64; ++i) {
                const int k = lane + i * 64;
                const float4 ps = *(const float4*)(Psum + (size_t)k * DD + cj);
                const float4 pq = *(const float4*)(Psq  + (size_t)k * DD + cj);
                s4.x += ps.x; s4.y += ps.y; s4.z += ps.z; s4.w += ps.w;
                q4.x += pq.x; q4.y += pq.y; q4.z += pq.z; q4.w += pq.w;
            }
            #pragma unroll
            for (int off = 32; off; off >>= 1) {
                s4.x += __shfl_down(s4.x, off, 64);
                s4.y += __shfl_down(s4.y, off, 64);
                s4.z += __shfl_down(s4.z, off, 64);
                s4.w += __shfl_down(s4.w, off, 64);
                q4.x += __shfl_down(q4.x, off, 64);
                q4.y += __shfl_down(q4.y, off, 64);
                q4.z += __shfl_down(q4.z, off, 64);
                q4.w += __shfl_down(q4.w, off, 64);
            }
            if (lane == 0) {
                const float invB = 1.0f / BB;
                float4 mu, inv, sh;
                mu.x = s4.x * invB; mu.y = s4.y * invB;
                mu.z = s4.z * invB; mu.w = s4.w * invB;
                inv.x = rsqrtf(q4.x * invB - mu.x * mu.x + BN_EPS);
                inv.y = rsqrtf(q4.y * invB - mu.y * mu.y + BN_EPS);
                inv.z = rsqrtf(q4.z * invB - mu.z * mu.z + BN_EPS);
                inv.w = rsqrtf(q4.w * invB - mu.w * mu.w + BN_EPS);
                sh.x = -mu.x * inv.x; sh.y = -mu.y * inv.y;
                sh.z = -mu.z * inv.z; sh.w = -mu.w * inv.w;
                *(float4*)(scale + cj) = inv;
                *(float4*)(shift + cj) = sh;
            }
        }

        grid_barrier(sync_, 2 * l + 1);

        // Apply BN to the register-resident residual.
        const float4 sc4 = *(const float4*)(scale + c);
        const float4 sh4 = *(const float4*)(shift + c);
        #pragma unroll
        for (int i = 0; i < ROWS; ++i) {
            float4 v = res[i];
            v.x = fmaf(v.x, sc4.x, sh4.x);
            v.y = fmaf(v.y, sc4.y, sh4.y);
            v.z = fmaf(v.z, sc4.z, sh4.z);
            v.w = fmaf(v.w, sc4.w, sh4.w);
            res[i] = v;
        }
    }

    // Final residual (post-BN of layer 3) -> output.
    #pragma unroll
    for (int i = 0; i < ROWS; ++i)
        *(float4*)(out + (size_t)(r0 + i) * DD + c) = res[i];
}

extern "C" void kernel_launch(void* const* d_in, const int* in_sizes, int n_in,
                              void* d_out, int out_size, void* d_ws, size_t ws_size,
                              hipStream_t stream) {
    const float* x  = (const float*)d_in[0];   // (B, D)
    const float* ww = (const float*)d_in[1];   // (NL, D)
    const float* wb = (const float*)d_in[2];   // (NL, D)
    float* out = (float*)d_out;
    float* ws  = (float*)d_ws;

    // Workspace: ~4.01 MB (well under previous 8.5 MB usage).
    float* Psum  = ws;                          // GRID_ * D
    float* Psq   = Psum + (size_t)GRID_ * DD;   // GRID_ * D
    float* scale = Psq  + (size_t)GRID_ * DD;   // D
    float* shift = scale + DD;                  // D
    unsigned int* sync_ = (unsigned int*)(shift + DD);  // NSYNC counters

    // Workspace is poisoned by the harness each iteration: barrier counters
    // must be re-zeroed inside the captured graph, before the main kernel.
    init_sync<<<1, 64, 0, stream>>>(sync_);
    crossnet_persistent<<<GRID_, NTHR, 0, stream>>>(
        x, ww, wb, out, Psum, Psq, scale, shift, sync_);
}